// Round 1
// baseline (387.635 us; speedup 1.0000x reference)
//
#include <hip/hip_runtime.h>

typedef __bf16 bf16;
typedef unsigned int u32;
typedef __attribute__((ext_vector_type(4))) float f32x4;
typedef __attribute__((ext_vector_type(8))) __bf16 bf16x8;
typedef __attribute__((ext_vector_type(4))) __bf16 bf16x4;

#define MFMA(a, b, c) __builtin_amdgcn_mfma_f32_16x16x32_bf16((a), (b), (c), 0, 0, 0)

#define M_TOT 8192
#define DIN 4096
#define DOUT 4096
#define DR 512

__device__ __forceinline__ void gll16(const void* g, void* l) {
  __builtin_amdgcn_global_load_lds((const __attribute__((address_space(1))) u32*)g,
                                   (__attribute__((address_space(3))) u32*)l, 16, 0, 0);
}

// ---------------- prep: V -> bf16 [512][4096] ----------------
__global__ __launch_bounds__(256) void prep_v_kernel(const float* __restrict__ vt,
                                                     const float* __restrict__ vd,
                                                     bf16* __restrict__ Vb) {
  int idx = blockIdx.x * 256 + threadIdx.x;  // one per 4 elems
  int e = idx * 4;
  int r = e >> 12, c = e & 4095;
  const float* src = (r < 64) ? (vt + ((size_t)r << 12) + c) : (vd + ((size_t)(r - 64) << 12) + c);
  float4 v = *reinterpret_cast<const float4*>(src);
  bf16x4 o = {(bf16)v.x, (bf16)v.y, (bf16)v.z, (bf16)v.w};
  *reinterpret_cast<bf16x4*>(Vb + e) = o;
}

// ---------------- prep: (U * s) -> bf16 [4096][512] ----------------
__global__ __launch_bounds__(256) void prep_u_kernel(const float* __restrict__ ut,
                                                     const float* __restrict__ ud,
                                                     const float* __restrict__ s,
                                                     bf16* __restrict__ Ub) {
  int idx = blockIdx.x * 256 + threadIdx.x;  // per 4 elems along r
  int o = idx >> 7;            // 128 quads per output row
  int rr = (idx & 127) * 4;
  const float* src = (rr < 64) ? (ut + (size_t)o * 64 + rr) : (ud + (size_t)o * 448 + (rr - 64));
  float4 v = *reinterpret_cast<const float4*>(src);
  float4 sv = *reinterpret_cast<const float4*>(s + rr);
  bf16x4 ov = {(bf16)(v.x * sv.x), (bf16)(v.y * sv.y), (bf16)(v.z * sv.z), (bf16)(v.w * sv.w)};
  *reinterpret_cast<bf16x4*>(Ub + (size_t)o * DR + rr) = ov;
}

// ---------------- GEMM1: t[8192][512] = x[8192][4096] * Vb[512][4096]^T ----------------
// BM=128 BN=128 BK=32, 512 threads (8 waves, wave tile 32x64), grid 256.
__global__ __launch_bounds__(512) void gemm1_kernel(const float* __restrict__ X,
                                                    const bf16* __restrict__ Vb,
                                                    bf16* __restrict__ T) {
  __shared__ alignas(16) bf16 As[2][128 * 40];  // padded stride 40 (reg-staged)
  __shared__ alignas(16) bf16 Bs[2][128 * 32];  // linear (global_load_lds)

  const int tid = threadIdx.x;
  const int bid = blockIdx.x;
  // XCD-grouped: the 4 N-tiles of one M-tile land on the same XCD (share x panel in L2)
  const int xcd = bid & 7, slot = bid >> 3;
  const int mt = xcd * 8 + (slot >> 2);
  const int nt = slot & 3;
  const int m0 = mt * 128, n0 = nt * 128;

  const int wid = tid >> 6, lane = tid & 63;
  const int wr = wid >> 1, wc = wid & 1;  // 4x2 wave grid
  const int lr = lane & 15, kg = lane >> 4;

  const int srow = tid >> 2, sseg = tid & 3;  // staging: 4 threads/row, 8 elems each
  const float* aG = X + (size_t)(m0 + srow) * DIN + sseg * 8;
  const bf16* bG = Vb + (size_t)(n0 + srow) * DIN + sseg * 8;
  const int aWoff = srow * 40 + sseg * 8;
  bf16* const bL0 = &Bs[0][wid * 512];
  bf16* const bL1 = &Bs[1][wid * 512];

  f32x4 acc[2][4];
  const f32x4 z = {0.f, 0.f, 0.f, 0.f};
#pragma unroll
  for (int i = 0; i < 2; ++i)
#pragma unroll
    for (int j = 0; j < 4; ++j) acc[i][j] = z;

  // prologue: stage kt=0 into buf 0
  {
    float4 v0 = *reinterpret_cast<const float4*>(aG);
    float4 v1 = *reinterpret_cast<const float4*>(aG + 4);
    bf16x8 w = {(bf16)v0.x, (bf16)v0.y, (bf16)v0.z, (bf16)v0.w,
                (bf16)v1.x, (bf16)v1.y, (bf16)v1.z, (bf16)v1.w};
    *reinterpret_cast<bf16x8*>(&As[0][aWoff]) = w;
    gll16(bG, bL0);
  }
  __syncthreads();

  const int NT = DIN / 32;  // 128
  for (int kt = 0; kt < NT; ++kt) {
    const int cur = kt & 1;
    float4 v0, v1;
    const bool pre = (kt + 1 < NT);
    if (pre) {
      const float* ag = aG + (size_t)(kt + 1) * 32;
      v0 = *reinterpret_cast<const float4*>(ag);
      v1 = *reinterpret_cast<const float4*>(ag + 4);
      gll16(bG + (size_t)(kt + 1) * 32, cur ? bL0 : bL1);
    }
    bf16x8 afr[2], bfr[4];
#pragma unroll
    for (int mi = 0; mi < 2; ++mi)
      afr[mi] = *reinterpret_cast<const bf16x8*>(&As[cur][(wr * 32 + mi * 16 + lr) * 40 + kg * 8]);
#pragma unroll
    for (int ni = 0; ni < 4; ++ni)
      bfr[ni] = *reinterpret_cast<const bf16x8*>(&Bs[cur][(wc * 64 + ni * 16 + lr) * 32 + kg * 8]);
#pragma unroll
    for (int mi = 0; mi < 2; ++mi)
#pragma unroll
      for (int ni = 0; ni < 4; ++ni)
        acc[mi][ni] = MFMA(afr[mi], bfr[ni], acc[mi][ni]);
    if (pre) {
      bf16x8 w = {(bf16)v0.x, (bf16)v0.y, (bf16)v0.z, (bf16)v0.w,
                  (bf16)v1.x, (bf16)v1.y, (bf16)v1.z, (bf16)v1.w};
      *reinterpret_cast<bf16x8*>(&As[cur ^ 1][aWoff]) = w;
    }
    __syncthreads();
  }

  // epilogue: C/D layout col = lane&15, row = (lane>>4)*4 + j
#pragma unroll
  for (int mi = 0; mi < 2; ++mi) {
    const int rbase = m0 + wr * 32 + mi * 16 + kg * 4;
#pragma unroll
    for (int ni = 0; ni < 4; ++ni) {
      const int c = n0 + wc * 64 + ni * 16 + lr;
      f32x4 a = acc[mi][ni];
#pragma unroll
      for (int j = 0; j < 4; ++j)
        T[(size_t)(rbase + j) * DR + c] = (bf16)a[j];
    }
  }
}

// ---------------- GEMM2: out[8192][4096] = t[8192][512] * Ub[4096][512]^T + bias ----------------
// BM=128 BN=128 BK=32, 256 threads (4 waves, wave tile 64x64), grid 2048.
__global__ __launch_bounds__(256) void gemm2_kernel(const bf16* __restrict__ T,
                                                    const bf16* __restrict__ Ub,
                                                    const float* __restrict__ bias,
                                                    float* __restrict__ Out) {
  __shared__ alignas(16) bf16 As[2][128 * 32];
  __shared__ alignas(16) bf16 Bs[2][128 * 32];

  const int tid = threadIdx.x;
  // XCD swizzle (2048 % 8 == 0 -> bijective)
  const int id = ((blockIdx.x & 7) << 8) | (blockIdx.x >> 3);
  const int mt = id >> 5, nt = id & 31;
  const int m0 = mt * 128, n0 = nt * 128;

  const int wid = tid >> 6, lane = tid & 63;
  const int wr = wid >> 1, wc = wid & 1;  // 2x2 wave grid
  const int lr = lane & 15, kg = lane >> 4;

  const int r0 = tid >> 2, s0 = tid & 3;  // staging chunk 0 (rows 0..63); chunk1 = +64 rows
  const bf16* aG0 = T + (size_t)(m0 + r0) * DR + s0 * 8;
  const bf16* bG0 = Ub + (size_t)(n0 + r0) * DR + s0 * 8;
  const bf16* aG1 = aG0 + (size_t)64 * DR;
  const bf16* bG1 = bG0 + (size_t)64 * DR;

  f32x4 acc[4][4];
  const f32x4 z = {0.f, 0.f, 0.f, 0.f};
#pragma unroll
  for (int i = 0; i < 4; ++i)
#pragma unroll
    for (int j = 0; j < 4; ++j) acc[i][j] = z;

  // prologue: stage kt=0 into buf 0
  {
    bf16* dA = &As[0][wid * 512];
    bf16* dB = &Bs[0][wid * 512];
    gll16(aG0, dA);
    gll16(aG1, dA + 2048);
    gll16(bG0, dB);
    gll16(bG1, dB + 2048);
  }
  __syncthreads();

  const int NT = DR / 32;  // 16
  for (int kt = 0; kt < NT; ++kt) {
    const int cur = kt & 1;
    const bool pre = (kt + 1 < NT);
    if (pre) {
      const size_t koff = (size_t)(kt + 1) * 32;
      bf16* dA = &As[cur ^ 1][wid * 512];
      bf16* dB = &Bs[cur ^ 1][wid * 512];
      gll16(aG0 + koff, dA);
      gll16(aG1 + koff, dA + 2048);
      gll16(bG0 + koff, dB);
      gll16(bG1 + koff, dB + 2048);
    }
    bf16x8 afr[4], bfr[4];
#pragma unroll
    for (int mi = 0; mi < 4; ++mi)
      afr[mi] = *reinterpret_cast<const bf16x8*>(&As[cur][(wr * 64 + mi * 16 + lr) * 32 + kg * 8]);
#pragma unroll
    for (int ni = 0; ni < 4; ++ni)
      bfr[ni] = *reinterpret_cast<const bf16x8*>(&Bs[cur][(wc * 64 + ni * 16 + lr) * 32 + kg * 8]);
#pragma unroll
    for (int mi = 0; mi < 4; ++mi)
#pragma unroll
      for (int ni = 0; ni < 4; ++ni)
        acc[mi][ni] = MFMA(afr[mi], bfr[ni], acc[mi][ni]);
    __syncthreads();
  }

  // epilogue with bias
#pragma unroll
  for (int ni = 0; ni < 4; ++ni) {
    const int c = n0 + wc * 64 + ni * 16 + lr;
    const float bv = bias[c];
#pragma unroll
    for (int mi = 0; mi < 4; ++mi) {
      const int rbase = m0 + wr * 64 + mi * 16 + kg * 4;
      f32x4 a = acc[mi][ni];
#pragma unroll
      for (int j = 0; j < 4; ++j)
        Out[(size_t)(rbase + j) * DOUT + c] = a[j] + bv;
    }
  }
}

extern "C" void kernel_launch(void* const* d_in, const int* in_sizes, int n_in,
                              void* d_out, int out_size, void* d_ws, size_t ws_size,
                              hipStream_t stream) {
  const float* x = (const float*)d_in[0];
  const float* u_t = (const float*)d_in[1];
  const float* s = (const float*)d_in[2];
  const float* v_t = (const float*)d_in[3];
  const float* u_d = (const float*)d_in[4];
  const float* v_d = (const float*)d_in[5];
  const float* bias = (const float*)d_in[6];
  float* out = (float*)d_out;

  bf16* Vb = (bf16*)d_ws;                                // 4 MiB: [512][4096]
  bf16* Ub = (bf16*)((char*)d_ws + (4u << 20));          // 4 MiB: [4096][512]
  bf16* T = (bf16*)((char*)d_ws + (8u << 20));           // 8 MiB: [8192][512]

  hipLaunchKernelGGL(prep_v_kernel, dim3(2048), dim3(256), 0, stream, v_t, v_d, Vb);
  hipLaunchKernelGGL(prep_u_kernel, dim3(2048), dim3(256), 0, stream, u_t, u_d, s, Ub);
  hipLaunchKernelGGL(gemm1_kernel, dim3(256), dim3(512), 0, stream, x, Vb, T);
  hipLaunchKernelGGL(gemm2_kernel, dim3(2048), dim3(256), 0, stream, T, Ub, bias, out);
}